// Round 1
// baseline (1636.037 us; speedup 1.0000x reference)
//
#include <hip/hip_runtime.h>

// PopNet: population-encode -> Linear(60,64) -> 25-step LIF -> Linear(64,3) -> LIF
// One thread per batch element. Memory-bound on ~910MB of output writes.

#define BINS   15
#define STEPS  25
#define NH     64   // hidden neurons
#define NO     3    // output neurons
#define NF     4    // input features

__global__ void popnet_kernel(const float* __restrict__ x,
                              const float* __restrict__ W1,
                              const float* __restrict__ b1,
                              const float* __restrict__ W2,
                              const float* __restrict__ b2,
                              float* __restrict__ out, int B)
{
    __shared__ float W1s[NH * 60];   // [64][60] row-major (torch [out,in])
    __shared__ float b1s[NH];
    __shared__ float W2s[NO * NH];   // [3][64]
    __shared__ float b2s[NO];

    for (int i = threadIdx.x; i < NH * 60; i += blockDim.x) W1s[i] = W1[i];
    for (int i = threadIdx.x; i < NH;      i += blockDim.x) b1s[i] = b1[i];
    for (int i = threadIdx.x; i < NO * NH; i += blockDim.x) W2s[i] = W2[i];
    if (threadIdx.x < NO) b2s[threadIdx.x] = b2[threadIdx.x];
    __syncthreads();

    const int b = blockIdx.x * blockDim.x + threadIdx.x;
    if (b >= B) return;

    // ---- population encode: idx per feature ----
    const float4 xv = *reinterpret_cast<const float4*>(x + (size_t)b * NF);
    float xf[NF] = {xv.x, xv.y, xv.z, xv.w};
    int idx[NF];
#pragma unroll
    for (int f = 0; f < NF; ++f) {
        float v = fminf(fmaxf(xf[f], 0.0f), 1.0f);
        int id = (int)(v * 14.0f);           // float32 mul then trunc, matches np
        id = min(max(id, 0), BINS - 1);
        idx[f] = id;
    }
    const int c0 = idx[0], c1 = 15 + idx[1], c2 = 30 + idx[2], c3 = 45 + idx[3];

    // ---- cur1[o] = W1[o,c0]+W1[o,c1]+W1[o,c2]+W1[o,c3] + b1[o] (ascending order, bias last) ----
    float cur1[NH];
#pragma unroll
    for (int o = 0; o < NH; ++o) {
        const float* row = W1s + o * 60;
        float s = __fadd_rn(__fadd_rn(__fadd_rn(row[c0], row[c1]), row[c2]), row[c3]);
        cur1[o] = __fadd_rn(s, b1s[o]);
    }

    float mem1[NH];
#pragma unroll
    for (int o = 0; o < NH; ++o) mem1[o] = 0.0f;
    float mem2[NO] = {0.0f, 0.0f, 0.0f};

    const size_t off1 = (size_t)STEPS * B * NO;            // start of spk1_rec
    const size_t off2 = off1 + (size_t)STEPS * B * NH;     // start of x_pop
    float* const out_spk2 = out;
    float* const out_spk1 = out + off1;
    float* const out_xpop = out + off2;

#pragma unroll 1
    for (int t = 0; t < STEPS; ++t) {
        float acc0 = 0.0f, acc1 = 0.0f, acc2 = 0.0f;       // cur2 accum (bias added last)
        float* const w1dst = out_spk1 + (size_t)t * B * NH + (size_t)b * NH;

#pragma unroll
        for (int n0 = 0; n0 < NH; n0 += 4) {
            const float4 w2a = *reinterpret_cast<const float4*>(&W2s[0 * NH + n0]);
            const float4 w2b = *reinterpret_cast<const float4*>(&W2s[1 * NH + n0]);
            const float4 w2c = *reinterpret_cast<const float4*>(&W2s[2 * NH + n0]);
            float4 sp;
            float sv[4];
#pragma unroll
            for (int j = 0; j < 4; ++j) {
                const int n = n0 + j;
                float m = mem1[n];
                const float reset = (m > 1.0f) ? 1.0f : 0.0f;          // reset1*THR == reset1
                m = __fsub_rn(__fadd_rn(__fmul_rn(0.8f, m), cur1[n]), reset);
                mem1[n] = m;
                const bool fire = (m > 1.0f);                           // (m - 1 > 0) exact by Sterbenz
                sv[j] = fire ? 1.0f : 0.0f;
                const float wa = (j == 0) ? w2a.x : (j == 1) ? w2a.y : (j == 2) ? w2a.z : w2a.w;
                const float wb = (j == 0) ? w2b.x : (j == 1) ? w2b.y : (j == 2) ? w2b.z : w2b.w;
                const float wc = (j == 0) ? w2c.x : (j == 1) ? w2c.y : (j == 2) ? w2c.z : w2c.w;
                acc0 = __fadd_rn(acc0, fire ? wa : 0.0f);
                acc1 = __fadd_rn(acc1, fire ? wb : 0.0f);
                acc2 = __fadd_rn(acc2, fire ? wc : 0.0f);
            }
            sp.x = sv[0]; sp.y = sv[1]; sp.z = sv[2]; sp.w = sv[3];
            *reinterpret_cast<float4*>(w1dst + n0) = sp;
        }

        // layer 2 LIF
        const float cu[NO] = {__fadd_rn(acc0, b2s[0]), __fadd_rn(acc1, b2s[1]), __fadd_rn(acc2, b2s[2])};
        float* const w2dst = out_spk2 + (size_t)t * B * NO + (size_t)b * NO;
#pragma unroll
        for (int k = 0; k < NO; ++k) {
            float m = mem2[k];
            const float reset = (m > 1.0f) ? 1.0f : 0.0f;
            m = __fsub_rn(__fadd_rn(__fmul_rn(0.8f, m), cu[k]), reset);
            mem2[k] = m;
            w2dst[k] = (m > 1.0f) ? 1.0f : 0.0f;
        }
    }

    // ---- x_pop one-hot write: [B,60] ----
    float* const xp = out_xpop + (size_t)b * 60;
#pragma unroll
    for (int j0 = 0; j0 < 60; j0 += 4) {
        float4 v;
        v.x = ((j0 + 0) % 15 == idx[(j0 + 0) / 15]) ? 1.0f : 0.0f;
        v.y = ((j0 + 1) % 15 == idx[(j0 + 1) / 15]) ? 1.0f : 0.0f;
        v.z = ((j0 + 2) % 15 == idx[(j0 + 2) / 15]) ? 1.0f : 0.0f;
        v.w = ((j0 + 3) % 15 == idx[(j0 + 3) / 15]) ? 1.0f : 0.0f;
        *reinterpret_cast<float4*>(xp + j0) = v;
    }
}

extern "C" void kernel_launch(void* const* d_in, const int* in_sizes, int n_in,
                              void* d_out, int out_size, void* d_ws, size_t ws_size,
                              hipStream_t stream) {
    const float* x  = (const float*)d_in[0];
    const float* W1 = (const float*)d_in[1];
    const float* b1 = (const float*)d_in[2];
    const float* W2 = (const float*)d_in[3];
    const float* b2 = (const float*)d_in[4];
    float* out = (float*)d_out;
    const int B = in_sizes[0] / NF;
    const int block = 256;
    const int grid = (B + block - 1) / block;
    popnet_kernel<<<grid, block, 0, stream>>>(x, W1, b1, W2, b2, out, B);
}

// Round 5
// 909.483 us; speedup vs baseline: 1.7989x; 1.7989x over previous
//
#include <hip/hip_runtime.h>

// PopNet: population-encode -> Linear(60,64) -> 25-step LIF -> Linear(64,3) -> LIF
// R2 logic, R4 fix: nontemporal stores need a clang ext_vector type, not HIP's
// float4 class. All global stores are block-contiguous via LDS staging (spike
// bitmasks), eliminating the partial-line write amplification seen in R1
// (FETCH 1.4GB / WRITE 2.1GB vs 0.91GB ideal).

#define BINS   15
#define STEPS  25
#define NH     64   // hidden neurons
#define NO     3    // output neurons
#define NF     4    // input features
#define TPB    256  // threads per block; B must be a multiple (131072/256=512)

typedef float f32x4 __attribute__((ext_vector_type(4)));

__global__ __launch_bounds__(TPB) void popnet_kernel(
                              const float* __restrict__ x,
                              const float* __restrict__ W1,
                              const float* __restrict__ b1,
                              const float* __restrict__ W2,
                              const float* __restrict__ b2,
                              float* __restrict__ out, int B)
{
    __shared__ float W1s[NH * 60];            // [64][60] row-major (torch [out,in])
    __shared__ float b1s[NH];
    __shared__ float W2s[NO * NH];            // [3][64]
    __shared__ float b2s[NO];
    __shared__ unsigned long long s1bits[TPB];   // per-thread 64 spike bits for current t
    __shared__ float s2f[TPB * NO];              // per-thread 3 spk2 floats for current t
    __shared__ unsigned int idxs[TPB];           // packed 4x4-bit bin indices

    const int tid = threadIdx.x;
    for (int i = tid; i < NH * 60; i += TPB) W1s[i] = W1[i];
    for (int i = tid; i < NH;      i += TPB) b1s[i] = b1[i];
    for (int i = tid; i < NO * NH; i += TPB) W2s[i] = W2[i];
    if (tid < NO) b2s[tid] = b2[tid];
    __syncthreads();

    const int blockStart = blockIdx.x * TPB;
    const int b = blockStart + tid;

    // ---- population encode: idx per feature ----
    const f32x4 xv = *reinterpret_cast<const f32x4*>(x + (size_t)b * NF);
    int idx[NF];
#pragma unroll
    for (int f = 0; f < NF; ++f) {
        float v = fminf(fmaxf(xv[f], 0.0f), 1.0f);
        int id = (int)(v * 14.0f);           // float32 mul then trunc, matches np
        id = min(max(id, 0), BINS - 1);
        idx[f] = id;
    }
    idxs[tid] = (unsigned)idx[0] | ((unsigned)idx[1] << 4) |
                ((unsigned)idx[2] << 8) | ((unsigned)idx[3] << 12);
    const int c0 = idx[0], c1 = 15 + idx[1], c2 = 30 + idx[2], c3 = 45 + idx[3];

    // ---- cur1[o] = W1[o,c0]+W1[o,c1]+W1[o,c2]+W1[o,c3] + b1[o] (ascending, bias last) ----
    float cur1[NH];
#pragma unroll
    for (int o = 0; o < NH; ++o) {
        const float* row = W1s + o * 60;
        float s = __fadd_rn(__fadd_rn(__fadd_rn(row[c0], row[c1]), row[c2]), row[c3]);
        cur1[o] = __fadd_rn(s, b1s[o]);
    }

    float mem1[NH];
#pragma unroll
    for (int o = 0; o < NH; ++o) mem1[o] = 0.0f;
    float mem2[NO] = {0.0f, 0.0f, 0.0f};

    const size_t off1 = (size_t)STEPS * B * NO;            // start of spk1_rec
    const size_t off2 = off1 + (size_t)STEPS * B * NH;     // start of x_pop
    float* const out_spk2 = out;
    float* const out_spk1 = out + off1;
    float* const out_xpop = out + off2;

#pragma unroll 1
    for (int t = 0; t < STEPS; ++t) {
        // ---- compute: LIF layer 1 (registers), pack spikes into bits ----
        float acc0 = 0.0f, acc1 = 0.0f, acc2 = 0.0f;
        unsigned long long bits = 0ull;
#pragma unroll
        for (int n = 0; n < NH; ++n) {
            float m = mem1[n];
            const float reset = (m > 1.0f) ? 1.0f : 0.0f;          // reset1*THR == reset1
            m = __fsub_rn(__fadd_rn(__fmul_rn(0.8f, m), cur1[n]), reset);
            mem1[n] = m;
            const bool fire = (m > 1.0f);                           // (m-1>0) exact by Sterbenz
            bits |= ((unsigned long long)(fire ? 1u : 0u)) << n;
            acc0 = __fadd_rn(acc0, fire ? W2s[0 * NH + n] : 0.0f);
            acc1 = __fadd_rn(acc1, fire ? W2s[1 * NH + n] : 0.0f);
            acc2 = __fadd_rn(acc2, fire ? W2s[2 * NH + n] : 0.0f);
        }
        s1bits[tid] = bits;

        // ---- LIF layer 2 ----
        const float cu[NO] = {__fadd_rn(acc0, b2s[0]), __fadd_rn(acc1, b2s[1]), __fadd_rn(acc2, b2s[2])};
#pragma unroll
        for (int k = 0; k < NO; ++k) {
            float m = mem2[k];
            const float reset = (m > 1.0f) ? 1.0f : 0.0f;
            m = __fsub_rn(__fadd_rn(__fmul_rn(0.8f, m), cu[k]), reset);
            mem2[k] = m;
            s2f[tid * NO + k] = (m > 1.0f) ? 1.0f : 0.0f;
        }
        __syncthreads();

        // ---- cooperative contiguous writes for this t ----
        // spk1 slice: TPB*64 floats = 4096 float4, 16 per thread, lane-consecutive
        float* const base1 = out_spk1 + (size_t)t * B * NH + (size_t)blockStart * NH;
#pragma unroll
        for (int i = 0; i < 16; ++i) {
            const int f4 = tid + i * TPB;         // [0,4096)
            const unsigned long long w = s1bits[f4 >> 4];
            const int n0 = (f4 & 15) * 4;
            f32x4 v;
            v.x = (float)((w >> (n0 + 0)) & 1ull);
            v.y = (float)((w >> (n0 + 1)) & 1ull);
            v.z = (float)((w >> (n0 + 2)) & 1ull);
            v.w = (float)((w >> (n0 + 3)) & 1ull);
            __builtin_nontemporal_store(v, reinterpret_cast<f32x4*>(base1) + f4);
        }
        // spk2 slice: TPB*3 floats = 192 float4
        float* const base2 = out_spk2 + (size_t)t * B * NO + (size_t)blockStart * NO;
        if (tid < (TPB * NO) / 4) {
            f32x4 v;
            v.x = s2f[tid * 4 + 0];
            v.y = s2f[tid * 4 + 1];
            v.z = s2f[tid * 4 + 2];
            v.w = s2f[tid * 4 + 3];
            __builtin_nontemporal_store(v, reinterpret_cast<f32x4*>(base2) + tid);
        }
        __syncthreads();   // before next t overwrites s1bits/s2f
    }

    // ---- x_pop one-hot: TPB*60 floats = 3840 float4, 15 per thread ----
    float* const basex = out_xpop + (size_t)blockStart * 60;
#pragma unroll
    for (int i = 0; i < 15; ++i) {
        const int g = tid + i * TPB;              // [0,3840)
        const int bb = g / 15;
        const int r = g - bb * 15;
        const unsigned pk = idxs[bb];
        const int j0 = r * 4;
        f32x4 v;
#pragma unroll
        for (int k = 0; k < 4; ++k) {
            const int j = j0 + k;
            const int feat = j / 15;
            const int bin = j - feat * 15;
            v[k] = (bin == (int)((pk >> (feat * 4)) & 15u)) ? 1.0f : 0.0f;
        }
        __builtin_nontemporal_store(v, reinterpret_cast<f32x4*>(basex) + g);
    }
}

extern "C" void kernel_launch(void* const* d_in, const int* in_sizes, int n_in,
                              void* d_out, int out_size, void* d_ws, size_t ws_size,
                              hipStream_t stream) {
    const float* x  = (const float*)d_in[0];
    const float* W1 = (const float*)d_in[1];
    const float* b1 = (const float*)d_in[2];
    const float* W2 = (const float*)d_in[3];
    const float* b2 = (const float*)d_in[4];
    float* out = (float*)d_out;
    const int B = in_sizes[0] / NF;
    popnet_kernel<<<B / TPB, TPB, 0, stream>>>(x, W1, b1, W2, b2, out, B);
}

// Round 7
// 907.726 us; speedup vs baseline: 1.8023x; 1.0019x over previous
//
#include <hip/hip_runtime.h>

// PopNet: population-encode -> Linear(60,64) -> 25-step LIF -> Linear(64,3) -> LIF
// R6 (resubmit after broker timeout): in-loop __syncthreads() drains vmcnt(0)
// (all outstanding global stores) 50x per block. Replace with raw
// "s_waitcnt lgkmcnt(0); s_barrier" (LDS-only ordering; stores stay in flight)
// + double-buffered LDS staging so only ONE barrier per step is needed.
// Store pattern unchanged from R5 (block-contiguous nontemporal float4;
// kernel ~326us, write floor ~145us at the fill's 6.27TB/s).

#define BINS   15
#define STEPS  25
#define NH     64   // hidden neurons
#define NO     3    // output neurons
#define NF     4    // input features
#define TPB    256  // threads per block; B must be a multiple (131072/256=512)

typedef float f32x4 __attribute__((ext_vector_type(4)));

// LDS-only barrier: order ds ops, do NOT drain global stores (vmcnt untouched).
#define LDS_BARRIER() asm volatile("s_waitcnt lgkmcnt(0)\n\ts_barrier" ::: "memory")

__global__ __launch_bounds__(TPB) void popnet_kernel(
                              const float* __restrict__ x,
                              const float* __restrict__ W1,
                              const float* __restrict__ b1,
                              const float* __restrict__ W2,
                              const float* __restrict__ b2,
                              float* __restrict__ out, int B)
{
    __shared__ float W1s[NH * 60];               // [64][60] row-major (torch [out,in])
    __shared__ float b1s[NH];
    __shared__ float W2s[NO * NH];               // [3][64]
    __shared__ float b2s[NO];
    __shared__ unsigned long long s1bits[2][TPB];   // double-buffered spike bits
    __shared__ float s2f[2][TPB * NO];              // double-buffered spk2 floats
    __shared__ unsigned int idxs[TPB];              // packed 4x4-bit bin indices

    const int tid = threadIdx.x;
    for (int i = tid; i < NH * 60; i += TPB) W1s[i] = W1[i];
    for (int i = tid; i < NH;      i += TPB) b1s[i] = b1[i];
    for (int i = tid; i < NO * NH; i += TPB) W2s[i] = W2[i];
    if (tid < NO) b2s[tid] = b2[tid];
    __syncthreads();   // once, before loop: no outstanding stores yet

    const int blockStart = blockIdx.x * TPB;
    const int b = blockStart + tid;

    // ---- population encode: idx per feature ----
    const f32x4 xv = *reinterpret_cast<const f32x4*>(x + (size_t)b * NF);
    int idx[NF];
#pragma unroll
    for (int f = 0; f < NF; ++f) {
        float v = fminf(fmaxf(xv[f], 0.0f), 1.0f);
        int id = (int)(v * 14.0f);           // float32 mul then trunc, matches np
        id = min(max(id, 0), BINS - 1);
        idx[f] = id;
    }
    idxs[tid] = (unsigned)idx[0] | ((unsigned)idx[1] << 4) |
                ((unsigned)idx[2] << 8) | ((unsigned)idx[3] << 12);
    const int c0 = idx[0], c1 = 15 + idx[1], c2 = 30 + idx[2], c3 = 45 + idx[3];

    // ---- cur1[o] = W1[o,c0]+W1[o,c1]+W1[o,c2]+W1[o,c3] + b1[o] (ascending, bias last) ----
    float cur1[NH];
#pragma unroll
    for (int o = 0; o < NH; ++o) {
        const float* row = W1s + o * 60;
        float s = __fadd_rn(__fadd_rn(__fadd_rn(row[c0], row[c1]), row[c2]), row[c3]);
        cur1[o] = __fadd_rn(s, b1s[o]);
    }

    float mem1[NH];
#pragma unroll
    for (int o = 0; o < NH; ++o) mem1[o] = 0.0f;
    float mem2[NO] = {0.0f, 0.0f, 0.0f};

    const size_t off1 = (size_t)STEPS * B * NO;            // start of spk1_rec
    const size_t off2 = off1 + (size_t)STEPS * B * NH;     // start of x_pop
    float* const out_spk2 = out;
    float* const out_spk1 = out + off1;
    float* const out_xpop = out + off2;

    int cur = 0;
#pragma unroll 1
    for (int t = 0; t < STEPS; ++t) {
        // ---- compute: LIF layer 1 (registers), pack spikes into bits ----
        float acc0 = 0.0f, acc1 = 0.0f, acc2 = 0.0f;
        unsigned long long bits = 0ull;
#pragma unroll
        for (int n = 0; n < NH; ++n) {
            float m = mem1[n];
            const float reset = (m > 1.0f) ? 1.0f : 0.0f;          // reset1*THR == reset1
            m = __fsub_rn(__fadd_rn(__fmul_rn(0.8f, m), cur1[n]), reset);
            mem1[n] = m;
            const bool fire = (m > 1.0f);                           // (m-1>0) exact by Sterbenz
            bits |= ((unsigned long long)(fire ? 1u : 0u)) << n;
            acc0 = __fadd_rn(acc0, fire ? W2s[0 * NH + n] : 0.0f);
            acc1 = __fadd_rn(acc1, fire ? W2s[1 * NH + n] : 0.0f);
            acc2 = __fadd_rn(acc2, fire ? W2s[2 * NH + n] : 0.0f);
        }
        s1bits[cur][tid] = bits;

        // ---- LIF layer 2 ----
        const float cu[NO] = {__fadd_rn(acc0, b2s[0]), __fadd_rn(acc1, b2s[1]), __fadd_rn(acc2, b2s[2])};
#pragma unroll
        for (int k = 0; k < NO; ++k) {
            float m = mem2[k];
            const float reset = (m > 1.0f) ? 1.0f : 0.0f;
            m = __fsub_rn(__fadd_rn(__fmul_rn(0.8f, m), cu[k]), reset);
            mem2[k] = m;
            s2f[cur][tid * NO + k] = (m > 1.0f) ? 1.0f : 0.0f;
        }

        // one LDS-only barrier: make this t's ds_writes visible; stores from the
        // previous t remain in flight (no vmcnt drain). Double buffer makes the
        // write->read of the NEXT iteration race-free without a second barrier.
        LDS_BARRIER();

        // ---- cooperative contiguous writes for this t ----
        // spk1 slice: TPB*64 floats = 4096 float4, 16 per thread, lane-consecutive
        float* const base1 = out_spk1 + (size_t)t * B * NH + (size_t)blockStart * NH;
#pragma unroll
        for (int i = 0; i < 16; ++i) {
            const int f4 = tid + i * TPB;         // [0,4096)
            const unsigned long long w = s1bits[cur][f4 >> 4];
            const int n0 = (f4 & 15) * 4;
            f32x4 v;
            v.x = (float)((w >> (n0 + 0)) & 1ull);
            v.y = (float)((w >> (n0 + 1)) & 1ull);
            v.z = (float)((w >> (n0 + 2)) & 1ull);
            v.w = (float)((w >> (n0 + 3)) & 1ull);
            __builtin_nontemporal_store(v, reinterpret_cast<f32x4*>(base1) + f4);
        }
        // spk2 slice: TPB*3 floats = 192 float4
        float* const base2 = out_spk2 + (size_t)t * B * NO + (size_t)blockStart * NO;
        if (tid < (TPB * NO) / 4) {
            f32x4 v;
            v.x = s2f[cur][tid * 4 + 0];
            v.y = s2f[cur][tid * 4 + 1];
            v.z = s2f[cur][tid * 4 + 2];
            v.w = s2f[cur][tid * 4 + 3];
            __builtin_nontemporal_store(v, reinterpret_cast<f32x4*>(base2) + tid);
        }
        cur ^= 1;
    }

    // ---- x_pop one-hot: TPB*60 floats = 3840 float4, 15 per thread ----
    // idxs[] was written before the t-loop; 25 barriers since => visible.
    float* const basex = out_xpop + (size_t)blockStart * 60;
#pragma unroll
    for (int i = 0; i < 15; ++i) {
        const int g = tid + i * TPB;              // [0,3840)
        const int bb = g / 15;
        const int r = g - bb * 15;
        const unsigned pk = idxs[bb];
        const int j0 = r * 4;
        f32x4 v;
#pragma unroll
        for (int k = 0; k < 4; ++k) {
            const int j = j0 + k;
            const int feat = j / 15;
            const int bin = j - feat * 15;
            v[k] = (bin == (int)((pk >> (feat * 4)) & 15u)) ? 1.0f : 0.0f;
        }
        __builtin_nontemporal_store(v, reinterpret_cast<f32x4*>(basex) + g);
    }
}

extern "C" void kernel_launch(void* const* d_in, const int* in_sizes, int n_in,
                              void* d_out, int out_size, void* d_ws, size_t ws_size,
                              hipStream_t stream) {
    const float* x  = (const float*)d_in[0];
    const float* W1 = (const float*)d_in[1];
    const float* b1 = (const float*)d_in[2];
    const float* W2 = (const float*)d_in[3];
    const float* b2 = (const float*)d_in[4];
    float* out = (float*)d_out;
    const int B = in_sizes[0] / NF;
    popnet_kernel<<<B / TPB, TPB, 0, stream>>>(x, W1, b1, W2, b2, out, B);
}